// Round 17
// baseline (2159.281 us; speedup 1.0000x reference)
//
#include <hip/hip_runtime.h>
#include <stdint.h>

// IntegratedNCA: 64 NCA steps. B=8, CH=16, H=W=96, HID=128, WDIM=128.
// Multi-launch (per-step kernel = the global sync). Phase B (life masking)
// fused into the NEXT step's staging: X_s = Y_{s-1} * life_{s-1} in LDS.
//
// R17 = R14 (NHWC state, pk_fma MLP, b128 perception) + 2 PIXELS/THREAD:
// tile 16x8 (128 px), 576 blocks x 256 thr, split-4. Each thread owns
// (rr,c) and (rr+4,c): every fetched weight feeds 48 pk_fma instead of 24,
// attacking the weight-fetch stall that caps VALUBusy at ~30%. R10's
// version of this regressed on NCHW write amplification; NHWC stores one
// float4 per (px,quarter) so that channel is gone (R14: WRITE=ideal).
// R16's register ping-pong spilled (WRITE 22MB scratch) -- this uses no
// extra weight registers. Threefry/M split across waves (no redundancy).
//
// PRNG: JAX threefry, jax_threefry_partitionable=True (green R2/R5-R16):
//   split: key[i]  = threefry2x32(0,42, 0, i)   (host-side, passed as args)
//   bits : bits[p] = o0^o1, (o0,o1)=threefry2x32(key, 0, p); uniform<0.5 <=> bits>>31==0

#define CHN 16
#define HIDN 128
#define WD 128
#define NB 8
#define NH 96
#define NW 96
#define NSTEPS 64
#define TW 16
#define TH 8
#define PLANE (NH*NW)          // 9216
#define TILES_X (NW/TW)        // 6
#define TILES_Y (NH/TH)        // 12
#define TPI (TILES_X*TILES_Y)  // 72
#define NBLK (NB*TPI)          // 576
#define HW_ (TH+2)             // 10 staged rows (halo 1)
#define WW_ (TW+2)             // 18 staged cols (halo 1)
#define NF4 (HW_*WW_*4)        // 720 staged float4s
#define NT 256

typedef float v2f __attribute__((ext_vector_type(2)));

__host__ __device__ __forceinline__ uint32_t rotl(uint32_t v, int d){ return (v<<d)|(v>>(32-d)); }

__host__ __device__ __forceinline__ void threefry2x32(uint32_t k0, uint32_t k1,
                                                      uint32_t x0, uint32_t x1,
                                                      uint32_t &o0, uint32_t &o1){
  uint32_t k2 = k0 ^ k1 ^ 0x1BD11BDAu;
  x0 += k0; x1 += k1;
  x0 += x1; x1 = rotl(x1,13); x1 ^= x0;
  x0 += x1; x1 = rotl(x1,15); x1 ^= x0;
  x0 += x1; x1 = rotl(x1,26); x1 ^= x0;
  x0 += x1; x1 = rotl(x1, 6); x1 ^= x0;
  x0 += k1; x1 += k2 + 1u;
  x0 += x1; x1 = rotl(x1,17); x1 ^= x0;
  x0 += x1; x1 = rotl(x1,29); x1 ^= x0;
  x0 += x1; x1 = rotl(x1,16); x1 ^= x0;
  x0 += x1; x1 = rotl(x1,24); x1 ^= x0;
  x0 += k2; x1 += k0 + 2u;
  x0 += x1; x1 = rotl(x1,13); x1 ^= x0;
  x0 += x1; x1 = rotl(x1,15); x1 ^= x0;
  x0 += x1; x1 = rotl(x1,26); x1 ^= x0;
  x0 += x1; x1 = rotl(x1, 6); x1 ^= x0;
  x0 += k0; x1 += k1 + 3u;
  x0 += x1; x1 = rotl(x1,17); x1 ^= x0;
  x0 += x1; x1 = rotl(x1,29); x1 ^= x0;
  x0 += x1; x1 = rotl(x1,16); x1 ^= x0;
  x0 += x1; x1 = rotl(x1,24); x1 ^= x0;
  x0 += k1; x1 += k2 + 4u;
  x0 += x1; x1 = rotl(x1,13); x1 ^= x0;
  x0 += x1; x1 = rotl(x1,15); x1 ^= x0;
  x0 += x1; x1 = rotl(x1,26); x1 ^= x0;
  x0 += x1; x1 = rotl(x1, 6); x1 ^= x0;
  x0 += k2; x1 += k0 + 5u;
  o0 = x0; o1 = x1;
}

// Pre: w1eff[128][32] natural layout (cols 0..15 = W1[:, :16]; cols 16..31 =
// folded perception pairs P[cc] = W1[:,16+2cc]+W1[:,17+2cc]) -- v2f-readable.
// w2t[128][16] = W2^T, c1[8][128] = b1 + W1[:,48:176].w[b].
__global__ __launch_bounds__(256) void nca_pre(
    const float* __restrict__ w, const float* __restrict__ W1,
    const float* __restrict__ b1, const float* __restrict__ W2,
    float* __restrict__ w1eff, float* __restrict__ w2t, float* __restrict__ c1)
{
  const int b = blockIdx.x, t = threadIdx.x;
  if (b == 0){
    for (int idx = t; idx < HIDN*32; idx += 256){
      int n = idx >> 5, k = idx & 31;
      float v;
      if (k < 16) v = W1[n*176 + k];
      else { int cc = k - 16; v = W1[n*176 + 16 + 2*cc] + W1[n*176 + 17 + 2*cc]; }
      w1eff[idx] = v;
    }
    for (int idx = t; idx < HIDN*CHN; idx += 256){
      int n = idx >> 4, cc = idx & 15;
      w2t[idx] = W2[cc*HIDN + n];
    }
  }
  if (t < HIDN){
    float s = b1[t];
    const float* wrow = W1 + t*176 + 48;
    const float* wb = w + b*WD;
    #pragma unroll 8
    for (int k = 0; k < WD; ++k) s = fmaf(wrow[k], wb[k], s);
    c1[b*HIDN + t] = s;
  }
}

// perception for pixel at tile coords (r,c) from NHWC LDS tile (halo-1).
__device__ __forceinline__ void perceive_nhwc(const float xs[HW_][WW_][20],
                                              int r, int c, v2f* xp, v2f* pp){
  #define LD4(dr,dc,k4) (*(const float4*)&xs[r+(dr)][c+(dc)][(k4)*4])
  const v2f two = (v2f){2.f, 2.f};
  #pragma unroll
  for (int k4 = 0; k4 < 4; ++k4){
    float4 v = LD4(1,1,k4);
    xp[2*k4]   = (v2f){v.x, v.y};
    xp[2*k4+1] = (v2f){v.z, v.w};
  }
  #pragma unroll
  for (int k4 = 0; k4 < 2; ++k4){      // sx -> ch 0..7
    float4 a = LD4(0,2,k4), b0 = LD4(0,0,k4);
    float4 d = LD4(1,2,k4), e = LD4(1,0,k4);
    float4 f = LD4(2,2,k4), g = LD4(2,0,k4);
    v2f a0 = (v2f){a.x,a.y}, a1 = (v2f){a.z,a.w};
    v2f b0v= (v2f){b0.x,b0.y},b1v= (v2f){b0.z,b0.w};
    v2f d0 = (v2f){d.x,d.y}, d1 = (v2f){d.z,d.w};
    v2f e0 = (v2f){e.x,e.y}, e1 = (v2f){e.z,e.w};
    v2f f0 = (v2f){f.x,f.y}, f1 = (v2f){f.z,f.w};
    v2f g0 = (v2f){g.x,g.y}, g1 = (v2f){g.z,g.w};
    pp[2*k4]   = (a0-b0v) + two*(d0-e0) + (f0-g0);
    pp[2*k4+1] = (a1-b1v) + two*(d1-e1) + (f1-g1);
  }
  #pragma unroll
  for (int k4 = 2; k4 < 4; ++k4){      // sy -> ch 8..15
    float4 a = LD4(2,0,k4), b0 = LD4(0,0,k4);
    float4 d = LD4(2,1,k4), e = LD4(0,1,k4);
    float4 f = LD4(2,2,k4), g = LD4(0,2,k4);
    v2f a0 = (v2f){a.x,a.y}, a1 = (v2f){a.z,a.w};
    v2f b0v= (v2f){b0.x,b0.y},b1v= (v2f){b0.z,b0.w};
    v2f d0 = (v2f){d.x,d.y}, d1 = (v2f){d.z,d.w};
    v2f e0 = (v2f){e.x,e.y}, e1 = (v2f){e.z,e.w};
    v2f f0 = (v2f){f.x,f.y}, f1 = (v2f){f.z,f.w};
    v2f g0 = (v2f){g.x,g.y}, g1 = (v2f){g.z,g.w};
    pp[2*k4]   = (a0-b0v) + two*(d0-e0) + (f0-g0);
    pp[2*k4+1] = (a1-b1v) + two*(d1-e1) + (f1-g1);
  }
  #undef LD4
}

// One NCA step. Block = 16x8 tile (128 px) x 4 hidden quarters; each thread
// owns pixels (rr,c) and (rr+4,c). q = wave id (0..3), wave-uniform.
template<bool FIRST>
__global__ __launch_bounds__(NT, 3) void nca_step(
    const float* __restrict__ Xin,          // x (NCHW) if FIRST, else Y_{s-1} (NHWC)
    const unsigned char* __restrict__ Mp,   // M_{s-1} (ignored if FIRST)
    const float* __restrict__ w1eff, const float* __restrict__ w2t,
    const float* __restrict__ c1,
    uint32_t key0, uint32_t key1,
    float* __restrict__ Yn, unsigned char* __restrict__ Mn)  // Yn NHWC
{
  __shared__ float xs[HW_][WW_][20];    // 14400 B: X tile+halo1, NHWC, pad 20
  __shared__ float ya[TH+4][TW+4];      //   960 B: Y alpha + halo 2 (12x20)
  __shared__ float lifes[HW_][WW_];     //   720 B
  __shared__ float ufs[128];            //   512 B: update factor per px
  __shared__ float red[4][CHN][128];    // 32768 B: partials, lane=px -> conflict-free

  const int T = blockIdx.x;
  const int b = T & 7;                  // image == XCD (%8 round-robin heuristic)
  const int t = T >> 3;
  const int tw0 = (t % TILES_X)*TW, th0 = (t / TILES_X)*TH;
  const int tid = threadIdx.x;

  if (FIRST){
    // one-time: scalar stage from NCHW x into NHWC LDS
    for (int idx = tid; idx < CHN*HW_*WW_; idx += NT){
      int ch = idx / (HW_*WW_), rem = idx % (HW_*WW_);
      int hh = rem / WW_, ww = rem % WW_;
      int g2 = th0 - 1 + hh, w2 = tw0 - 1 + ww;
      float v = 0.f;
      if ((unsigned)g2 < NH && (unsigned)w2 < NW)
        v = Xin[((b*CHN + ch)*NH + g2)*NW + w2];
      xs[hh][ww][ch] = v;
    }
  } else {
    // Y alpha + halo 2 (zero-pad OOB: 0 <= 0.1 never flips the mask)
    if (tid < (TH+4)*(TW+4)){
      int hh = tid / (TW+4), ww = tid % (TW+4);
      int g2 = th0 - 2 + hh, w2 = tw0 - 2 + ww;
      float v = 0.f;
      if ((unsigned)g2 < NH && (unsigned)w2 < NW)
        v = Xin[(size_t)(b*PLANE + g2*NW + w2)*CHN + 3];
      ya[hh][ww] = v;
    }
    // coalesced float4 staging of Y tile+halo1 into regs
    float4 xr[3];
    #pragma unroll
    for (int i = 0; i < 3; ++i){
      int idx = tid + i*NT;
      float4 v = make_float4(0.f,0.f,0.f,0.f);
      if (idx < NF4){
        int hh = idx / (WW_*4);
        int rem = idx % (WW_*4);
        int ww = rem >> 2, k4 = rem & 3;
        int g2 = th0 - 1 + hh, w2 = tw0 - 1 + ww;
        if ((unsigned)g2 < NH && (unsigned)w2 < NW)
          v = *(const float4*)(Xin + (size_t)(b*PLANE + g2*NW + w2)*CHN + k4*4);
      }
      xr[i] = v;
    }
    __syncthreads();                    // ya visible
    if (tid < HW_*WW_){                 // life over tile + halo 1 (180 elems)
      int hh = tid / WW_, ww = tid % WW_;
      int g2 = th0 - 1 + hh, w2 = tw0 - 1 + ww;
      float lf = 0.f;
      if ((unsigned)g2 < NH && (unsigned)w2 < NW){
        float mx = ya[hh][ww];
        #pragma unroll
        for (int dr = 0; dr < 3; ++dr)
          #pragma unroll
          for (int dc = 0; dc < 3; ++dc)
            mx = fmaxf(mx, ya[hh+dr][ww+dc]);
        lf = (Mp[b*PLANE + g2*NW + w2] && (mx > 0.1f)) ? 1.f : 0.f;
      }
      lifes[hh][ww] = lf;
    }
    __syncthreads();                    // lifes visible
    #pragma unroll
    for (int i = 0; i < 3; ++i){
      int idx = tid + i*NT;
      if (idx < NF4){
        int hh = idx / (WW_*4);
        int rem = idx % (WW_*4);
        int ww = rem >> 2, k4 = rem & 3;
        float lf = lifes[hh][ww];
        float4 v = xr[i];
        v.x *= lf; v.y *= lf; v.z *= lf; v.w *= lf;
        *(float4*)&xs[hh][ww][k4*4] = v;   // 16B-aligned (80B row stride)
      }
    }
  }
  __syncthreads();

  const int px = tid & 63;          // column-group index (64 pairs)
  const int q  = tid >> 6;          // hidden quarter == wave id (0..3)
  const int c = px & 15, rr = px >> 4;    // pixels (rr,c) and (rr+4,c)
  const int gh0 = th0 + rr, gh1 = gh0 + 4, gw = tw0 + c;
  const int pos0 = b*PLANE + gh0*NW + gw;
  const int pos1 = pos0 + 4*NW;

  v2f xpA[8], ppA[8], xpB[8], ppB[8];
  perceive_nhwc(xs, rr,   c, xpA, ppA);
  perceive_nhwc(xs, rr+4, c, xpB, ppB);

  // threefry / M split across the 4 waves (zero redundancy)
  if (q == 0){
    uint32_t o0, o1;
    threefry2x32(key0, key1, 0u, (uint32_t)pos0, o0, o1);
    ufs[px] = ((((o0 ^ o1) >> 31) == 0u) && (xpA[1].y > 0.1f)) ? 1.f : 0.f;
  } else if (q == 1){
    uint32_t o0, o1;
    threefry2x32(key0, key1, 0u, (uint32_t)pos1, o0, o1);
    ufs[64 + px] = ((((o0 ^ o1) >> 31) == 0u) && (xpB[1].y > 0.1f)) ? 1.f : 0.f;
  } else if (q == 2){
    float mx = xs[rr][c][3];
    #pragma unroll
    for (int dr = 0; dr < 3; ++dr)
      #pragma unroll
      for (int dc = 0; dc < 3; ++dc)
        mx = fmaxf(mx, xs[rr+dr][c+dc][3]);
    Mn[pos0] = (mx > 0.1f) ? (unsigned char)1 : (unsigned char)0;
  } else {
    float mx = xs[rr+4][c][3];
    #pragma unroll
    for (int dr = 0; dr < 3; ++dr)
      #pragma unroll
      for (int dc = 0; dc < 3; ++dc)
        mx = fmaxf(mx, xs[rr+4+dr][c+dc][3]);
    Mn[pos1] = (mx > 0.1f) ? (unsigned char)1 : (unsigned char)0;
  }

  // ---- packed MLP: 32 hidden units per quarter, 2 pixels per thread.
  // One weight fetch (24 v2f + c1) feeds 48 pk_fma.
  v2f accA[8], accB[8];
  #pragma unroll
  for (int i = 0; i < 8; ++i){ accA[i] = (v2f){0.f,0.f}; accB[i] = (v2f){0.f,0.f}; }
  // q is wave-uniform; readfirstlane keeps weight addresses provably scalar
  // (s_load path; SGPR=112 in green R5-R14 kernels).
  const int nbase = __builtin_amdgcn_readfirstlane(q) << 5;
  const float* c1b = c1 + b*HIDN;

  #pragma unroll 4
  for (int nn = 0; nn < 32; ++nn){
    const int n = nbase + nn;
    const v2f* wx = (const v2f*)(w1eff + (n << 5));   // 8 x-pairs then 8 p-pairs
    float c1n = c1b[n];
    v2f h01a = (v2f){c1n, 0.f}, h23a = (v2f){0.f, 0.f};
    v2f h01b = (v2f){c1n, 0.f}, h23b = (v2f){0.f, 0.f};
    #pragma unroll
    for (int k = 0; k < 8; ++k){
      v2f w1k = wx[k], wpk = wx[8+k];
      h01a = __builtin_elementwise_fma(xpA[k], w1k, h01a);  // v_pk_fma_f32
      h23a = __builtin_elementwise_fma(ppA[k], wpk, h23a);
      h01b = __builtin_elementwise_fma(xpB[k], w1k, h01b);
      h23b = __builtin_elementwise_fma(ppB[k], wpk, h23b);
    }
    float hva = fmaxf((h01a.x + h01a.y) + (h23a.x + h23a.y), 0.f);
    float hvb = fmaxf((h01b.x + h01b.y) + (h23b.x + h23b.y), 0.f);
    v2f hva2 = (v2f){hva, hva}, hvb2 = (v2f){hvb, hvb};
    const v2f* w2p = (const v2f*)(w2t + (n << 4));    // 8 channel-pairs
    #pragma unroll
    for (int cc2 = 0; cc2 < 8; ++cc2){
      v2f wv = w2p[cc2];
      accA[cc2] = __builtin_elementwise_fma(hva2, wv, accA[cc2]);
      accB[cc2] = __builtin_elementwise_fma(hvb2, wv, accB[cc2]);
    }
  }

  #pragma unroll
  for (int cc2 = 0; cc2 < 8; ++cc2){
    red[q][2*cc2  ][px]      = accA[cc2].x;
    red[q][2*cc2+1][px]      = accA[cc2].y;
    red[q][2*cc2  ][64 + px] = accB[cc2].x;
    red[q][2*cc2+1][64 + px] = accB[cc2].y;
  }
  __syncthreads();

  // epilogue: quarter q writes channels 4q..4q+3 for both pixels (NHWC f4)
  {
    float uf0 = ufs[px], uf1 = ufs[64 + px];
    int ch = q << 2;
    float a0 = ((red[0][ch+0][px] + red[1][ch+0][px]) + (red[2][ch+0][px] + red[3][ch+0][px]));
    float a1 = ((red[0][ch+1][px] + red[1][ch+1][px]) + (red[2][ch+1][px] + red[3][ch+1][px]));
    float a2 = ((red[0][ch+2][px] + red[1][ch+2][px]) + (red[2][ch+2][px] + red[3][ch+2][px]));
    float a3 = ((red[0][ch+3][px] + red[1][ch+3][px]) + (red[2][ch+3][px] + red[3][ch+3][px]));
    // xpA[2q],xpA[2q+1] hold channels 4q..4q+3 of pixel A (likewise B)
    float4 oA = make_float4(fmaf(a0, uf0, xpA[2*q].x), fmaf(a1, uf0, xpA[2*q].y),
                            fmaf(a2, uf0, xpA[2*q+1].x), fmaf(a3, uf0, xpA[2*q+1].y));
    *(float4*)(Yn + (size_t)pos0*CHN + q*4) = oA;
    float b0 = ((red[0][ch+0][64+px] + red[1][ch+0][64+px]) + (red[2][ch+0][64+px] + red[3][ch+0][64+px]));
    float b1 = ((red[0][ch+1][64+px] + red[1][ch+1][64+px]) + (red[2][ch+1][64+px] + red[3][ch+1][64+px]));
    float b2 = ((red[0][ch+2][64+px] + red[1][ch+2][64+px]) + (red[2][ch+2][64+px] + red[3][ch+2][64+px]));
    float b3 = ((red[0][ch+3][64+px] + red[1][ch+3][64+px]) + (red[2][ch+3][64+px] + red[3][ch+3][64+px]));
    float4 oB = make_float4(fmaf(b0, uf1, xpB[2*q].x), fmaf(b1, uf1, xpB[2*q].y),
                            fmaf(b2, uf1, xpB[2*q+1].x), fmaf(b3, uf1, xpB[2*q+1].y));
    *(float4*)(Yn + (size_t)pos1*CHN + q*4) = oB;
  }
}

// Final: out (NCHW) = Y_63 (NHWC) * (M_63 & living(Y_63 alpha)); 16x8 tiles.
__global__ __launch_bounds__(256) void nca_final(
    const float* __restrict__ Yp, const unsigned char* __restrict__ Mp,
    float* __restrict__ out)
{
  __shared__ float ya[TH+4][TW+4];     // 12x20
  __shared__ float lifes[TH][TW];
  const int T = blockIdx.x;
  const int b = T & 7;
  const int t = T >> 3;
  const int tw0 = (t % TILES_X)*TW, th0 = (t / TILES_X)*TH;
  const int tid = threadIdx.x;
  if (tid < (TH+4)*(TW+4)){
    int hh = tid / (TW+4), ww = tid % (TW+4);
    int g2 = th0 - 2 + hh, w2 = tw0 - 2 + ww;
    float v = 0.f;
    if ((unsigned)g2 < NH && (unsigned)w2 < NW)
      v = Yp[(size_t)(b*PLANE + g2*NW + w2)*CHN + 3];
    ya[hh][ww] = v;
  }
  __syncthreads();
  if (tid < TH*TW){
    int i = tid >> 4, j = tid & 15;
    float mx = ya[i+2][j+2];
    #pragma unroll
    for (int dr = 0; dr < 3; ++dr)
      #pragma unroll
      for (int dc = 0; dc < 3; ++dc)
        mx = fmaxf(mx, ya[i+1+dr][j+1+dc]);
    lifes[i][j] = (Mp[b*PLANE + (th0+i)*NW + (tw0+j)] && (mx > 0.1f)) ? 1.f : 0.f;
  }
  __syncthreads();
  for (int idx = tid; idx < CHN*TH*TW; idx += 256){
    int ch = idx >> 7, p = idx & 127;
    int i = p >> 4, j = p & 15;
    int pos = b*PLANE + (th0+i)*NW + (tw0+j);
    out[((b*CHN + ch)*NH + th0 + i)*NW + tw0 + j] = Yp[(size_t)pos*CHN + ch] * lifes[i][j];
  }
}

extern "C" void kernel_launch(void* const* d_in, const int* in_sizes, int n_in,
                              void* d_out, int out_size, void* d_ws, size_t ws_size,
                              hipStream_t stream) {
  const float* x  = (const float*)d_in[0];
  const float* w  = (const float*)d_in[1];
  // d_in[2] = sobel (hard-coded), d_in[6] = steps (=64, hard-coded)
  const float* W1 = (const float*)d_in[3];
  const float* b1 = (const float*)d_in[4];
  const float* W2 = (const float*)d_in[5];
  float* out = (float*)d_out;
  char* ws = (char*)d_ws;

  size_t off = 0;
  float*    w1eff = (float*)(ws + off);    off += (size_t)HIDN*32*4;
  float*    w2t   = (float*)(ws + off);    off += (size_t)HIDN*CHN*4;
  float*    c1    = (float*)(ws + off);    off += (size_t)NB*HIDN*4;
  float*    Yb0   = (float*)(ws + off);    off += (size_t)NB*CHN*PLANE*4;  // NHWC
  float*    Yb1   = (float*)(ws + off);    off += (size_t)NB*CHN*PLANE*4;  // NHWC
  unsigned char* Mb0 = (unsigned char*)(ws + off); off += (size_t)NB*PLANE;
  unsigned char* Mb1 = (unsigned char*)(ws + off); off += (size_t)NB*PLANE;
  (void)ws_size; (void)in_sizes; (void)n_in; (void)out_size;

  // step keys are input-independent constants: compute on host, pass as args
  uint32_t k0[NSTEPS], k1[NSTEPS];
  for (int s = 0; s < NSTEPS; ++s) threefry2x32(0u, 42u, 0u, (uint32_t)s, k0[s], k1[s]);

  nca_pre<<<dim3(NB), dim3(256), 0, stream>>>(w, W1, b1, W2, w1eff, w2t, c1);

  nca_step<true><<<dim3(NBLK), dim3(NT), 0, stream>>>(
      x, Mb1 /*unused*/, w1eff, w2t, c1, k0[0], k1[0], Yb0, Mb0);
  for (int s = 1; s < NSTEPS; ++s){
    const float* Yp = (s & 1) ? Yb0 : Yb1;
    float*       Yn = (s & 1) ? Yb1 : Yb0;
    const unsigned char* Mq = (s & 1) ? Mb0 : Mb1;
    unsigned char*       Mn = (s & 1) ? Mb1 : Mb0;
    nca_step<false><<<dim3(NBLK), dim3(NT), 0, stream>>>(
        Yp, Mq, w1eff, w2t, c1, k0[s], k1[s], Yn, Mn);
  }
  // s=63 (odd) wrote Yb1/Mb1
  nca_final<<<dim3(NBLK), dim3(256), 0, stream>>>(Yb1, Mb1, out);
}

// Round 18
// 1360.118 us; speedup vs baseline: 1.5876x; 1.5876x over previous
//
#include <hip/hip_runtime.h>
#include <stdint.h>

// IntegratedNCA: 64 NCA steps. B=8, CH=16, H=W=96, HID=128, WDIM=128.
// Multi-launch (per-step kernel = the global sync). Phase B (life masking)
// fused into the NEXT step's staging: X_s = Y_{s-1} * life_{s-1} in LDS.
//
// R18 = R14 (champion: NHWC state, pk_fma MLP, b128 perception, dedup
// threefry) + W1 WEIGHTS IN LDS: w1eff (16KB) staged per kernel with 4
// coalesced float4 loads/thread; layer-1 weight reads become wave-uniform
// ds_read_b128 BROADCASTS (same-address = free), bypassing the scalar cache.
// Theory: MLP working set (24KB) thrashes the ~16KB K$, stalling ALL waves
// on the same resource -> VALUBusy pinned at 30% regardless of occupancy
// (R7/R9/R16/R17 all failed to move it). w2t+c1 (8.5KB) stay s_load and now
// fit K$. LDS 41.5KB -> 3 blocks/CU. MLP unroll 2 to cap VGPRs.
// Geometry locked: 1152 blocks x 256 thr, 16x4 tiles, split-4, image%8 XCD.
//
// PRNG: JAX threefry, jax_threefry_partitionable=True (green R2/R5-R17):
//   split: key[i]  = threefry2x32(0,42, 0, i)   (host-side, passed as args)
//   bits : bits[p] = o0^o1, (o0,o1)=threefry2x32(key, 0, p); uniform<0.5 <=> bits>>31==0

#define CHN 16
#define HIDN 128
#define WD 128
#define NB 8
#define NH 96
#define NW 96
#define NSTEPS 64
#define TW 16
#define TH 4
#define PLANE (NH*NW)          // 9216
#define TILES_X (NW/TW)        // 6
#define TILES_Y (NH/TH)        // 24
#define TPI (TILES_X*TILES_Y)  // 144
#define NBLK (NB*TPI)          // 1152
#define HW_ (TH+2)             // 6 staged rows (halo 1)
#define WW_ (TW+2)             // 18 staged cols (halo 1)
#define NF4 (HW_*WW_*4)        // 432 staged float4s
#define NT 256

typedef float v2f __attribute__((ext_vector_type(2)));

__host__ __device__ __forceinline__ uint32_t rotl(uint32_t v, int d){ return (v<<d)|(v>>(32-d)); }

__host__ __device__ __forceinline__ void threefry2x32(uint32_t k0, uint32_t k1,
                                                      uint32_t x0, uint32_t x1,
                                                      uint32_t &o0, uint32_t &o1){
  uint32_t k2 = k0 ^ k1 ^ 0x1BD11BDAu;
  x0 += k0; x1 += k1;
  x0 += x1; x1 = rotl(x1,13); x1 ^= x0;
  x0 += x1; x1 = rotl(x1,15); x1 ^= x0;
  x0 += x1; x1 = rotl(x1,26); x1 ^= x0;
  x0 += x1; x1 = rotl(x1, 6); x1 ^= x0;
  x0 += k1; x1 += k2 + 1u;
  x0 += x1; x1 = rotl(x1,17); x1 ^= x0;
  x0 += x1; x1 = rotl(x1,29); x1 ^= x0;
  x0 += x1; x1 = rotl(x1,16); x1 ^= x0;
  x0 += x1; x1 = rotl(x1,24); x1 ^= x0;
  x0 += k2; x1 += k0 + 2u;
  x0 += x1; x1 = rotl(x1,13); x1 ^= x0;
  x0 += x1; x1 = rotl(x1,15); x1 ^= x0;
  x0 += x1; x1 = rotl(x1,26); x1 ^= x0;
  x0 += x1; x1 = rotl(x1, 6); x1 ^= x0;
  x0 += k0; x1 += k1 + 3u;
  x0 += x1; x1 = rotl(x1,17); x1 ^= x0;
  x0 += x1; x1 = rotl(x1,29); x1 ^= x0;
  x0 += x1; x1 = rotl(x1,16); x1 ^= x0;
  x0 += x1; x1 = rotl(x1,24); x1 ^= x0;
  x0 += k1; x1 += k2 + 4u;
  x0 += x1; x1 = rotl(x1,13); x1 ^= x0;
  x0 += x1; x1 = rotl(x1,15); x1 ^= x0;
  x0 += x1; x1 = rotl(x1,26); x1 ^= x0;
  x0 += x1; x1 = rotl(x1, 6); x1 ^= x0;
  x0 += k2; x1 += k0 + 5u;
  o0 = x0; o1 = x1;
}

// Pre: w1eff[128][32] natural layout (cols 0..15 = W1[:, :16]; cols 16..31 =
// folded perception pairs P[cc] = W1[:,16+2cc]+W1[:,17+2cc]) -- v2f-readable.
// w2t[128][16] = W2^T, c1[8][128] = b1 + W1[:,48:176].w[b].
__global__ __launch_bounds__(256) void nca_pre(
    const float* __restrict__ w, const float* __restrict__ W1,
    const float* __restrict__ b1, const float* __restrict__ W2,
    float* __restrict__ w1eff, float* __restrict__ w2t, float* __restrict__ c1)
{
  const int b = blockIdx.x, t = threadIdx.x;
  if (b == 0){
    for (int idx = t; idx < HIDN*32; idx += 256){
      int n = idx >> 5, k = idx & 31;
      float v;
      if (k < 16) v = W1[n*176 + k];
      else { int cc = k - 16; v = W1[n*176 + 16 + 2*cc] + W1[n*176 + 17 + 2*cc]; }
      w1eff[idx] = v;
    }
    for (int idx = t; idx < HIDN*CHN; idx += 256){
      int n = idx >> 4, cc = idx & 15;
      w2t[idx] = W2[cc*HIDN + n];
    }
  }
  if (t < HIDN){
    float s = b1[t];
    const float* wrow = W1 + t*176 + 48;
    const float* wb = w + b*WD;
    #pragma unroll 8
    for (int k = 0; k < WD; ++k) s = fmaf(wrow[k], wb[k], s);
    c1[b*HIDN + t] = s;
  }
}

// One NCA step. Block = 16x4 pixel tile x 4 hidden quarters (256 thr, q=wave).
// FIRST: X = input x (NCHW). Else: X = Yp*(Mp & living(Yp alpha)), Yp NHWC.
template<bool FIRST>
__global__ __launch_bounds__(NT, 3) void nca_step(
    const float* __restrict__ Xin,          // x (NCHW) if FIRST, else Y_{s-1} (NHWC)
    const unsigned char* __restrict__ Mp,   // M_{s-1} (ignored if FIRST)
    const float* __restrict__ w1eff, const float* __restrict__ w2t,
    const float* __restrict__ c1,
    uint32_t key0, uint32_t key1,
    float* __restrict__ Yn, unsigned char* __restrict__ Mn)  // Yn NHWC
{
  __shared__ __align__(16) float w1s[HIDN*32]; // 16384 B: layer-1 weights (LDS-resident)
  __shared__ float xs[HW_][WW_][20];    //  8640 B: X tile+halo1, NHWC, pad 20
  __shared__ float ya[TH+4][TW+4];      //   640 B: Y alpha + halo 2 (8x20)
  __shared__ float lifes[HW_][WW_];     //   432 B
  __shared__ float ufs[64];             //   256 B: update factor per px
  __shared__ float red[4][CHN][64];     // 16384 B: partials, lane=px -> 2-way (free)

  const int T = blockIdx.x;
  const int b = T & 7;                  // image == XCD (%8 round-robin heuristic)
  const int t = T >> 3;
  const int tw0 = (t % TILES_X)*TW, th0 = (t / TILES_X)*TH;
  const int tid = threadIdx.x;

  // ---- stage w1eff -> LDS (4 coalesced float4/thread; L2-resident source)
  {
    const float4* src = (const float4*)w1eff;
    float4* dst = (float4*)w1s;
    #pragma unroll
    for (int i = 0; i < 4; ++i) dst[tid + i*NT] = src[tid + i*NT];
  }

  if (FIRST){
    // one-time: scalar stage from NCHW x into NHWC LDS
    for (int idx = tid; idx < CHN*HW_*WW_; idx += NT){
      int ch = idx / (HW_*WW_), rem = idx % (HW_*WW_);
      int hh = rem / WW_, ww = rem % WW_;
      int g2 = th0 - 1 + hh, w2 = tw0 - 1 + ww;
      float v = 0.f;
      if ((unsigned)g2 < NH && (unsigned)w2 < NW)
        v = Xin[((b*CHN + ch)*NH + g2)*NW + w2];
      xs[hh][ww][ch] = v;
    }
  } else {
    // Y alpha + halo 2 (zero-pad OOB: 0 <= 0.1 never flips the mask)
    if (tid < (TH+4)*(TW+4)){
      int hh = tid / (TW+4), ww = tid % (TW+4);
      int g2 = th0 - 2 + hh, w2 = tw0 - 2 + ww;
      float v = 0.f;
      if ((unsigned)g2 < NH && (unsigned)w2 < NW)
        v = Xin[(size_t)(b*PLANE + g2*NW + w2)*CHN + 3];
      ya[hh][ww] = v;
    }
    // coalesced float4 staging of Y tile+halo1 into regs
    float4 xr[2];
    #pragma unroll
    for (int i = 0; i < 2; ++i){
      int idx = tid + i*NT;
      float4 v = make_float4(0.f,0.f,0.f,0.f);
      if (idx < NF4){
        int hh = idx / (WW_*4);
        int rem = idx % (WW_*4);
        int ww = rem >> 2, k4 = rem & 3;
        int g2 = th0 - 1 + hh, w2 = tw0 - 1 + ww;
        if ((unsigned)g2 < NH && (unsigned)w2 < NW)
          v = *(const float4*)(Xin + (size_t)(b*PLANE + g2*NW + w2)*CHN + k4*4);
      }
      xr[i] = v;
    }
    __syncthreads();                    // ya visible
    if (tid < HW_*WW_){                 // life over tile + halo 1 (108 elems)
      int hh = tid / WW_, ww = tid % WW_;
      int g2 = th0 - 1 + hh, w2 = tw0 - 1 + ww;
      float lf = 0.f;
      if ((unsigned)g2 < NH && (unsigned)w2 < NW){
        float mx = ya[hh][ww];
        #pragma unroll
        for (int dr = 0; dr < 3; ++dr)
          #pragma unroll
          for (int dc = 0; dc < 3; ++dc)
            mx = fmaxf(mx, ya[hh+dr][ww+dc]);
        lf = (Mp[b*PLANE + g2*NW + w2] && (mx > 0.1f)) ? 1.f : 0.f;
      }
      lifes[hh][ww] = lf;
    }
    __syncthreads();                    // lifes visible
    #pragma unroll
    for (int i = 0; i < 2; ++i){
      int idx = tid + i*NT;
      if (idx < NF4){
        int hh = idx / (WW_*4);
        int rem = idx % (WW_*4);
        int ww = rem >> 2, k4 = rem & 3;
        float lf = lifes[hh][ww];
        float4 v = xr[i];
        v.x *= lf; v.y *= lf; v.z *= lf; v.w *= lf;
        *(float4*)&xs[hh][ww][k4*4] = v;   // 16B-aligned (80B row stride)
      }
    }
  }
  __syncthreads();

  const int px = tid & 63;          // pixel in 16x4 tile
  const int q  = tid >> 6;          // hidden quarter == wave id (0..3)
  const int c = px & 15, r = px >> 4;
  const int gh = th0 + r, gw = tw0 + c;
  const int pos = b*PLANE + gh*NW + gw;

  // perception via b128 LDS reads; conv arithmetic in v2f (natural pairs
  // (2k,2k+1) share the same filter: k4<2 -> sx, k4>=2 -> sy)
  #define LD4(dr,dc,k4) (*(const float4*)&xs[r+(dr)][c+(dc)][(k4)*4])
  const v2f two = (v2f){2.f, 2.f};
  float4 xc4[4];
  v2f xp[8], pp[8];
  #pragma unroll
  for (int k4 = 0; k4 < 4; ++k4){
    xc4[k4] = LD4(1,1,k4);
    xp[2*k4]   = (v2f){xc4[k4].x, xc4[k4].y};
    xp[2*k4+1] = (v2f){xc4[k4].z, xc4[k4].w};
  }
  #pragma unroll
  for (int k4 = 0; k4 < 2; ++k4){      // sx -> ch 0..7
    float4 a = LD4(0,2,k4), b0 = LD4(0,0,k4);
    float4 d = LD4(1,2,k4), e = LD4(1,0,k4);
    float4 f = LD4(2,2,k4), g = LD4(2,0,k4);
    v2f a0 = (v2f){a.x,a.y}, a1 = (v2f){a.z,a.w};
    v2f b0v= (v2f){b0.x,b0.y},b1v= (v2f){b0.z,b0.w};
    v2f d0 = (v2f){d.x,d.y}, d1 = (v2f){d.z,d.w};
    v2f e0 = (v2f){e.x,e.y}, e1 = (v2f){e.z,e.w};
    v2f f0 = (v2f){f.x,f.y}, f1 = (v2f){f.z,f.w};
    v2f g0 = (v2f){g.x,g.y}, g1 = (v2f){g.z,g.w};
    pp[2*k4]   = (a0-b0v) + two*(d0-e0) + (f0-g0);
    pp[2*k4+1] = (a1-b1v) + two*(d1-e1) + (f1-g1);
  }
  #pragma unroll
  for (int k4 = 2; k4 < 4; ++k4){      // sy -> ch 8..15
    float4 a = LD4(2,0,k4), b0 = LD4(0,0,k4);
    float4 d = LD4(2,1,k4), e = LD4(0,1,k4);
    float4 f = LD4(2,2,k4), g = LD4(0,2,k4);
    v2f a0 = (v2f){a.x,a.y}, a1 = (v2f){a.z,a.w};
    v2f b0v= (v2f){b0.x,b0.y},b1v= (v2f){b0.z,b0.w};
    v2f d0 = (v2f){d.x,d.y}, d1 = (v2f){d.z,d.w};
    v2f e0 = (v2f){e.x,e.y}, e1 = (v2f){e.z,e.w};
    v2f f0 = (v2f){f.x,f.y}, f1 = (v2f){f.z,f.w};
    v2f g0 = (v2f){g.x,g.y}, g1 = (v2f){g.z,g.w};
    pp[2*k4]   = (a0-b0v) + two*(d0-e0) + (f0-g0);
    pp[2*k4+1] = (a1-b1v) + two*(d1-e1) + (f1-g1);
  }
  #undef LD4

  // threefry deduped to wave 0; M (pre_life of masked X alpha) by wave 1
  if (q == 0){
    uint32_t o0, o1;
    threefry2x32(key0, key1, 0u, (uint32_t)pos, o0, o1);
    ufs[px] = ((((o0 ^ o1) >> 31) == 0u) && (xc4[0].w > 0.1f)) ? 1.f : 0.f;
  } else if (q == 1){
    float mx = xs[r][c][3];
    #pragma unroll
    for (int dr = 0; dr < 3; ++dr)
      #pragma unroll
      for (int dc = 0; dc < 3; ++dc)
        mx = fmaxf(mx, xs[r+dr][c+dc][3]);
    Mn[pos] = (mx > 0.1f) ? (unsigned char)1 : (unsigned char)0;
  }

  // ---- packed MLP: 32 hidden units per quarter; layer-1 weights from LDS
  // (wave-uniform ds_read_b128 broadcast, no scalar-cache involvement),
  // layer-2 weights + c1 via s_load (8.5KB now fits K$).
  v2f acc2[8];
  #pragma unroll
  for (int i = 0; i < 8; ++i) acc2[i] = (v2f){0.f, 0.f};
  // q is wave-uniform; readfirstlane keeps the base provably scalar.
  const int nbase = __builtin_amdgcn_readfirstlane(q) << 5;
  const float* c1b = c1 + b*HIDN;

  #pragma unroll 2
  for (int nn = 0; nn < 32; ++nn){
    const int n = nbase + nn;
    const v2f* wx = (const v2f*)(w1s + (n << 5));     // LDS: 8 x-pairs then 8 p-pairs
    v2f h01 = (v2f){c1b[n], 0.f};
    v2f h23 = (v2f){0.f, 0.f};
    #pragma unroll
    for (int k = 0; k < 8; ++k){
      h01 = __builtin_elementwise_fma(xp[k], wx[k],   h01);  // v_pk_fma_f32
      h23 = __builtin_elementwise_fma(pp[k], wx[8+k], h23);
    }
    float hv = fmaxf((h01.x + h01.y) + (h23.x + h23.y), 0.f);
    v2f hvv = (v2f){hv, hv};
    const v2f* w2p = (const v2f*)(w2t + (n << 4));    // 8 channel-pairs (s_load)
    #pragma unroll
    for (int cc2 = 0; cc2 < 8; ++cc2)
      acc2[cc2] = __builtin_elementwise_fma(hvv, w2p[cc2], acc2[cc2]);
  }

  #pragma unroll
  for (int cc2 = 0; cc2 < 8; ++cc2){
    red[q][2*cc2  ][px] = acc2[cc2].x;
    red[q][2*cc2+1][px] = acc2[cc2].y;
  }
  __syncthreads();

  // epilogue: quarter q writes channels 4q..4q+3 as ONE float4 (NHWC)
  {
    float uf = ufs[px];
    int ch = q << 2;
    float v0 = ((red[0][ch+0][px] + red[1][ch+0][px]) + (red[2][ch+0][px] + red[3][ch+0][px]));
    float v1 = ((red[0][ch+1][px] + red[1][ch+1][px]) + (red[2][ch+1][px] + red[3][ch+1][px]));
    float v2 = ((red[0][ch+2][px] + red[1][ch+2][px]) + (red[2][ch+2][px] + red[3][ch+2][px]));
    float v3 = ((red[0][ch+3][px] + red[1][ch+3][px]) + (red[2][ch+3][px] + red[3][ch+3][px]));
    float4 o = make_float4(fmaf(v0, uf, xc4[q].x), fmaf(v1, uf, xc4[q].y),
                           fmaf(v2, uf, xc4[q].z), fmaf(v3, uf, xc4[q].w));
    *(float4*)(Yn + (size_t)pos*CHN + q*4) = o;
  }
}

// Final: out (NCHW) = Y_63 (NHWC) * (M_63 & living(Y_63 alpha))
__global__ __launch_bounds__(256) void nca_final(
    const float* __restrict__ Yp, const unsigned char* __restrict__ Mp,
    float* __restrict__ out)
{
  __shared__ float ya[TH+4][TW+4];     // 8x20
  __shared__ float lifes[TH][TW];
  const int T = blockIdx.x;
  const int b = T & 7;
  const int t = T >> 3;
  const int tw0 = (t % TILES_X)*TW, th0 = (t / TILES_X)*TH;
  const int tid = threadIdx.x;
  if (tid < (TH+4)*(TW+4)){
    int hh = tid / (TW+4), ww = tid % (TW+4);
    int g2 = th0 - 2 + hh, w2 = tw0 - 2 + ww;
    float v = 0.f;
    if ((unsigned)g2 < NH && (unsigned)w2 < NW)
      v = Yp[(size_t)(b*PLANE + g2*NW + w2)*CHN + 3];
    ya[hh][ww] = v;
  }
  __syncthreads();
  if (tid < TH*TW){
    int i = tid >> 4, j = tid & 15;
    float mx = ya[i+2][j+2];
    #pragma unroll
    for (int dr = 0; dr < 3; ++dr)
      #pragma unroll
      for (int dc = 0; dc < 3; ++dc)
        mx = fmaxf(mx, ya[i+1+dr][j+1+dc]);
    lifes[i][j] = (Mp[b*PLANE + (th0+i)*NW + (tw0+j)] && (mx > 0.1f)) ? 1.f : 0.f;
  }
  __syncthreads();
  for (int idx = tid; idx < CHN*TH*TW; idx += 256){
    int ch = idx >> 6, p = idx & 63;
    int i = p >> 4, j = p & 15;
    int pos = b*PLANE + (th0+i)*NW + (tw0+j);
    out[((b*CHN + ch)*NH + th0 + i)*NW + tw0 + j] = Yp[(size_t)pos*CHN + ch] * lifes[i][j];
  }
}

extern "C" void kernel_launch(void* const* d_in, const int* in_sizes, int n_in,
                              void* d_out, int out_size, void* d_ws, size_t ws_size,
                              hipStream_t stream) {
  const float* x  = (const float*)d_in[0];
  const float* w  = (const float*)d_in[1];
  // d_in[2] = sobel (hard-coded), d_in[6] = steps (=64, hard-coded)
  const float* W1 = (const float*)d_in[3];
  const float* b1 = (const float*)d_in[4];
  const float* W2 = (const float*)d_in[5];
  float* out = (float*)d_out;
  char* ws = (char*)d_ws;

  size_t off = 0;
  float*    w1eff = (float*)(ws + off);    off += (size_t)HIDN*32*4;
  float*    w2t   = (float*)(ws + off);    off += (size_t)HIDN*CHN*4;
  float*    c1    = (float*)(ws + off);    off += (size_t)NB*HIDN*4;
  float*    Yb0   = (float*)(ws + off);    off += (size_t)NB*CHN*PLANE*4;  // NHWC
  float*    Yb1   = (float*)(ws + off);    off += (size_t)NB*CHN*PLANE*4;  // NHWC
  unsigned char* Mb0 = (unsigned char*)(ws + off); off += (size_t)NB*PLANE;
  unsigned char* Mb1 = (unsigned char*)(ws + off); off += (size_t)NB*PLANE;
  (void)ws_size; (void)in_sizes; (void)n_in; (void)out_size;

  // step keys are input-independent constants: compute on host, pass as args
  uint32_t k0[NSTEPS], k1[NSTEPS];
  for (int s = 0; s < NSTEPS; ++s) threefry2x32(0u, 42u, 0u, (uint32_t)s, k0[s], k1[s]);

  nca_pre<<<dim3(NB), dim3(256), 0, stream>>>(w, W1, b1, W2, w1eff, w2t, c1);

  nca_step<true><<<dim3(NBLK), dim3(NT), 0, stream>>>(
      x, Mb1 /*unused*/, w1eff, w2t, c1, k0[0], k1[0], Yb0, Mb0);
  for (int s = 1; s < NSTEPS; ++s){
    const float* Yp = (s & 1) ? Yb0 : Yb1;
    float*       Yn = (s & 1) ? Yb1 : Yb0;
    const unsigned char* Mq = (s & 1) ? Mb0 : Mb1;
    unsigned char*       Mn = (s & 1) ? Mb1 : Mb0;
    nca_step<false><<<dim3(NBLK), dim3(NT), 0, stream>>>(
        Yp, Mq, w1eff, w2t, c1, k0[s], k1[s], Yn, Mn);
  }
  // s=63 (odd) wrote Yb1/Mb1
  nca_final<<<dim3(NBLK), dim3(256), 0, stream>>>(Yb1, Mb1, out);
}